// Round 1
// baseline (874.260 us; speedup 1.0000x reference)
//
#include <hip/hip_runtime.h>

// CPQuadRankLayer: B=64, N=1024, C=4, R=64, D=128, fp32.
//   projected[b,n,c,r] = sum_i x[b,n,c,i] * factors[c,n,r,i]
//   p = projected / sqrt(mean_r(projected^2) + 1e-6)
//   merged[b,n,r] = p0*p1*p2*p3 * gain[n]
//   out[b,n,o] = sum_r merged[b,n,r] * factor_out[n,r,o] + mean_c x[b,n,c,o]
//
// Strategy: 1 block per n; 4 waves; lane = b. Wave-uniform factor reads ->
// SGPR operands (full 64-batch reuse in-register, factors read once from HBM).
// RMSNorm fully per-lane. Residual accumulated via LDS atomicAdd during the
// projection's x loads. Memory floor ~53us @ 6.3 TB/s.

constexpr int Bb = 64;
constexpr int Nn = 1024;
constexpr int Cc = 4;
constexpr int Dd = 128;
constexpr int Rr = 64;

__global__ __launch_bounds__(256, 1)
void cpquad_kernel(const float* __restrict__ x,
                   const float* __restrict__ factors,
                   const float* __restrict__ factor_out,
                   const float* __restrict__ gain,
                   float* __restrict__ out) {
  // res[b][i]: sum over c of x[b,n,c,i]; +1 pad -> bank (b+i)%32, conflict-free
  __shared__ float res[Bb][Dd + 1];
  // pbuf[c][b][r]: normalized projections; +1 pad -> bank (b+r)%32
  __shared__ float pbuf[Cc][Bb][Rr + 1];

  const int n   = blockIdx.x;
  const int tid = threadIdx.x;
  const int c   = __builtin_amdgcn_readfirstlane(tid >> 6);  // wave id, SGPR
  const int b   = tid & 63;                                   // lane = batch

  // zero the residual accumulator
  for (int idx = tid; idx < Bb * (Dd + 1); idx += 256)
    (&res[0][0])[idx] = 0.0f;
  __syncthreads();

  // ---------------- Phase 1: projection (wave c, lane b) ----------------
  const float*  xp  = x + ((((size_t)b * Nn + n) * Cc + c) * Dd);
  const float4* xp4 = (const float4*)xp;
  const float*  fp  = factors + (((size_t)c * Nn + n) * Rr) * Dd;  // wave-uniform

  float acc[Rr];
#pragma unroll
  for (int r = 0; r < Rr; ++r) acc[r] = 0.0f;

  // prefetch first 16-float x chunk
  float4 xv[4];
#pragma unroll
  for (int q = 0; q < 4; ++q) xv[q] = xp4[q];

#pragma unroll 1
  for (int i0 = 0; i0 < Dd; i0 += 16) {
    float xc[16];
#pragma unroll
    for (int q = 0; q < 4; ++q) {
      xc[4 * q + 0] = xv[q].x;
      xc[4 * q + 1] = xv[q].y;
      xc[4 * q + 2] = xv[q].z;
      xc[4 * q + 3] = xv[q].w;
    }
    if (i0 + 16 < Dd) {
#pragma unroll
      for (int q = 0; q < 4; ++q) xv[q] = xp4[(i0 >> 4) * 4 + 4 + q];
    }
    // residual accumulation (4 waves hit same slots -> LDS atomic)
#pragma unroll
    for (int j = 0; j < 16; ++j)
      atomicAdd(&res[b][i0 + j], xc[j]);
    // 64 ranks x 16 i: factor values are wave-uniform -> SGPR operand FMAs
#pragma unroll
    for (int r = 0; r < Rr; ++r) {
      const float* fr = fp + r * Dd + i0;
#pragma unroll
      for (int j = 0; j < 16; ++j)
        acc[r] = fmaf(fr[j], xc[j], acc[r]);
    }
  }

  // ---------------- Phase 2: RMSNorm over r (per-lane) ----------------
  float ss = 0.0f;
#pragma unroll
  for (int r = 0; r < Rr; ++r) ss = fmaf(acc[r], acc[r], ss);
  const float rinv = 1.0f / sqrtf(ss * (1.0f / Rr) + 1e-6f);
#pragma unroll
  for (int r = 0; r < Rr; ++r) pbuf[c][b][r] = acc[r] * rinv;

  __syncthreads();

  // ---------------- Phase 3: quartic merge (per-lane, r in regs) --------
  const float g = gain[n];
  float m[Rr];
#pragma unroll
  for (int r = 0; r < Rr; ++r)
    m[r] = pbuf[0][b][r] * pbuf[1][b][r] * pbuf[2][b][r] * pbuf[3][b][r] * g;

  // ---------------- Phase 4: output projection, wave c owns o-range -----
  const int o0 = c * 32;
  float acc2[32];
#pragma unroll
  for (int j = 0; j < 32; ++j) acc2[j] = 0.0f;

  const float* fo = factor_out + ((size_t)n * Rr) * Dd + o0;  // wave-uniform
#pragma unroll 8
  for (int r = 0; r < Rr; ++r) {
    const float mr = m[r];
#pragma unroll
    for (int j = 0; j < 32; ++j)
      acc2[j] = fmaf(fo[(size_t)r * Dd + j], mr, acc2[j]);
  }

  // residual (mean over 4 children) + store
  float* op = out + (((size_t)b * Nn + n) * Dd) + o0;
#pragma unroll
  for (int q = 0; q < 8; ++q) {
    float4 v;
    v.x = acc2[4 * q + 0] + res[b][o0 + 4 * q + 0] * 0.25f;
    v.y = acc2[4 * q + 1] + res[b][o0 + 4 * q + 1] * 0.25f;
    v.z = acc2[4 * q + 2] + res[b][o0 + 4 * q + 2] * 0.25f;
    v.w = acc2[4 * q + 3] + res[b][o0 + 4 * q + 3] * 0.25f;
    ((float4*)op)[q] = v;
  }
}

extern "C" void kernel_launch(void* const* d_in, const int* in_sizes, int n_in,
                              void* d_out, int out_size, void* d_ws, size_t ws_size,
                              hipStream_t stream) {
  const float* x          = (const float*)d_in[0];
  const float* factors    = (const float*)d_in[1];
  const float* factor_out = (const float*)d_in[2];
  const float* gain       = (const float*)d_in[3];
  float* out              = (float*)d_out;
  hipLaunchKernelGGL(cpquad_kernel, dim3(Nn), dim3(256), 0, stream,
                     x, factors, factor_out, gain, out);
}

// Round 2
// 730.314 us; speedup vs baseline: 1.1971x; 1.1971x over previous
//
#include <hip/hip_runtime.h>

// CPQuadRankLayer: B=64, N=1024, C=4, R=64, D=128, fp32.
//   projected[b,n,c,r] = sum_i x[b,n,c,i] * factors[c,n,r,i]
//   p = projected * rsqrt(mean_r(projected^2) + 1e-6)
//   merged[b,n,r] = p0*p1*p2*p3 * gain[n]
//   out[b,n,o] = sum_r merged[b,n,r] * factor_out[n,r,o] + 0.25*sum_c x[b,n,c,o]
//
// R2 design: block per n; 4 waves; wave=c, lane=b.
// Factors: global_load_lds (async 16B DMA) -> LDS double-buffer ->
// uniform-address ds_read_b128 broadcast (conflict-free) -> FMA.
// LDS ~49KB, __launch_bounds__(256,3) -> 3 blocks/CU (12 waves/CU).
// factor_out staged through the same LDS buffer for phase 4.
// Residual re-reads x in epilogue (L2-hot). VALU floor ~34us, HBM floor ~60us.

constexpr int Bb = 64;
constexpr int Nn = 1024;
constexpr int Cc = 4;
constexpr int Dd = 128;
constexpr int Rr = 64;
constexpr int IC = 16;            // i-chunk
constexpr int NCH = Dd / IC;      // 8 chunks

typedef __attribute__((address_space(3))) float lds_float;
typedef __attribute__((address_space(1))) const float gbl_float;

// async global->LDS, 16B per lane; LDS dst = wave-uniform base + lane*16.
// Generic shared pointer's low 32 bits == LDS byte offset (aperture is 4GiB
// aligned), so the integer-cast route to AS(3) is safe and always compiles.
__device__ __forceinline__ void ald16(const float* g, const float* l) {
  __builtin_amdgcn_global_load_lds((gbl_float*)g,
                                   (lds_float*)(uint32_t)(uintptr_t)l,
                                   16, 0, 0);
}

__global__ __launch_bounds__(256, 3)
void cpquad_kernel(const float* __restrict__ x,
                   const float* __restrict__ factors,
                   const float* __restrict__ factor_out,
                   const float* __restrict__ gain,
                   float* __restrict__ out) {
  // factor staging: [buf][c][r][i] ; 2*4*64*16*4B = 32 KiB.
  // Reused flat as factor_out[n] = [64r][128o] = 32 KiB in phase 4.
  __shared__ alignas(16) float Fbuf[2][Cc][Rr][IC];
  // merged product accumulator; stride 65 -> bank (b+r)%32, 2-way = free.
  __shared__ float pbuf[Bb][Rr + 1];

  const int n    = blockIdx.x;
  const int tid  = threadIdx.x;
  const int c    = __builtin_amdgcn_readfirstlane(tid >> 6);  // wave id (=child)
  const int lane = tid & 63;                                   // lane = batch b
  const int b    = lane;

  const float* fcn = factors + (((size_t)c * Nn + n) * Rr) * Dd;  // wave-uniform
  const float* xw  = x + (((size_t)b * Nn + n) * Cc + c) * Dd;    // per-lane
  const float4* xw4 = (const float4*)xw;

  // lane's slice of the factor DMA: r = (lane>>2) + 16j, i-quad = lane&3
  const float* fsrc = fcn + (size_t)(lane >> 2) * Dd + (lane & 3) * 4;

  // ---- stage chunk 0 + prefetch x chunk 0 ----
  {
    float* lb = &Fbuf[0][c][0][0];
#pragma unroll
    for (int j = 0; j < 4; ++j)
      ald16(fsrc + (size_t)j * 16 * Dd, lb + j * 16 * IC);
  }
  float4 cur[4], nxt[4];
#pragma unroll
  for (int q = 0; q < 4; ++q) cur[q] = xw4[q];

  const float g = gain[n];

  float acc[Rr];
#pragma unroll
  for (int r = 0; r < Rr; ++r) acc[r] = 0.0f;

  __syncthreads();  // drains vmcnt -> chunk-0 DMA complete

  // ---------------- Phase 1: projection ----------------
#pragma unroll 1
  for (int ch = 0; ch < NCH; ++ch) {
    const int p = ch & 1;
    if (ch + 1 < NCH) {
      // stage next factor chunk (async DMA into other buffer)
      float* lb = &Fbuf[p ^ 1][c][0][0];
      const float* gs = fsrc + (ch + 1) * IC;
#pragma unroll
      for (int j = 0; j < 4; ++j)
        ald16(gs + (size_t)j * 16 * Dd, lb + j * 16 * IC);
      // prefetch next x chunk
#pragma unroll
      for (int q = 0; q < 4; ++q) nxt[q] = xw4[(ch + 1) * 4 + q];
    }

    float xc[16];
#pragma unroll
    for (int q = 0; q < 4; ++q) {
      xc[4 * q + 0] = cur[q].x;
      xc[4 * q + 1] = cur[q].y;
      xc[4 * q + 2] = cur[q].z;
      xc[4 * q + 3] = cur[q].w;
    }

#pragma unroll 8
    for (int r = 0; r < Rr; ++r) {
      // uniform address -> ds_read_b128 broadcast, conflict-free
      const float4* fr = (const float4*)&Fbuf[p][c][r][0];
      float4 f0 = fr[0], f1 = fr[1], f2 = fr[2], f3 = fr[3];
      float a = acc[r];
      a = fmaf(f0.x, xc[0], a);  a = fmaf(f0.y, xc[1], a);
      a = fmaf(f0.z, xc[2], a);  a = fmaf(f0.w, xc[3], a);
      a = fmaf(f1.x, xc[4], a);  a = fmaf(f1.y, xc[5], a);
      a = fmaf(f1.z, xc[6], a);  a = fmaf(f1.w, xc[7], a);
      a = fmaf(f2.x, xc[8], a);  a = fmaf(f2.y, xc[9], a);
      a = fmaf(f2.z, xc[10], a); a = fmaf(f2.w, xc[11], a);
      a = fmaf(f3.x, xc[12], a); a = fmaf(f3.y, xc[13], a);
      a = fmaf(f3.z, xc[14], a); a = fmaf(f3.w, xc[15], a);
      acc[r] = a;
    }

#pragma unroll
    for (int q = 0; q < 4; ++q) cur[q] = nxt[q];
    __syncthreads();  // waves done reading buf p; next iter overwrites it
  }

  // ---- stage factor_out[n] (64x128 = 32 KiB) into Fbuf (now free) ----
  {
    float* fb = &Fbuf[0][0][0][0];
    const float* fog = factor_out + (size_t)n * Rr * Dd;
#pragma unroll
    for (int j = 0; j < 8; ++j) {
      const int sec = (j << 2) | c;               // wave-uniform section id
      ald16(fog + sec * 256 + (lane << 2), fb + sec * 256);
    }
  }

  // ---------------- Phase 2: RMSNorm (per-lane) ----------------
  float ss = 0.0f;
#pragma unroll
  for (int r = 0; r < Rr; ++r) ss = fmaf(acc[r], acc[r], ss);
  float scale = 1.0f / sqrtf(ss * (1.0f / Rr) + 1e-6f);
  if (c == 0) scale *= g;  // fold gain into wave 0's contribution

  // ---------------- Phase 3: quartic product, in-place over waves -------
#pragma unroll 1
  for (int w = 0; w < Cc; ++w) {
    if (c == w) {
      if (w == 0) {
#pragma unroll 8
        for (int r = 0; r < Rr; ++r) pbuf[b][r] = acc[r] * scale;
      } else {
#pragma unroll 8
        for (int r = 0; r < Rr; ++r) pbuf[b][r] *= acc[r] * scale;
      }
    }
    __syncthreads();  // also drains factor_out DMA by the last pass
  }

  // ---------------- Phase 4: output projection (wave c -> o-range) ------
  const int o0 = c * 32;
  float acc2[32];
#pragma unroll
  for (int j = 0; j < 32; ++j) acc2[j] = 0.0f;

  // residual loads issued early; consumed after the FMA loop
  const float* xr = x + ((size_t)b * Nn + n) * Cc * Dd + o0;
  float4 res[8];
#pragma unroll
  for (int q = 0; q < 8; ++q) {
    float4 s = ((const float4*)(xr + 0 * Dd))[q];
    float4 v1 = ((const float4*)(xr + 1 * Dd))[q];
    float4 v2 = ((const float4*)(xr + 2 * Dd))[q];
    float4 v3 = ((const float4*)(xr + 3 * Dd))[q];
    s.x += v1.x + v2.x + v3.x;  s.y += v1.y + v2.y + v3.y;
    s.z += v1.z + v2.z + v3.z;  s.w += v1.w + v2.w + v3.w;
    res[q] = s;
  }

  const float* fb = &Fbuf[0][0][0][0];
#pragma unroll 4
  for (int r = 0; r < Rr; ++r) {
    const float mr = pbuf[b][r];                       // 2-way bank = free
    const float4* row = (const float4*)(fb + r * Dd + o0);  // broadcast reads
#pragma unroll
    for (int q = 0; q < 8; ++q) {
      float4 f = row[q];
      acc2[4 * q + 0] = fmaf(f.x, mr, acc2[4 * q + 0]);
      acc2[4 * q + 1] = fmaf(f.y, mr, acc2[4 * q + 1]);
      acc2[4 * q + 2] = fmaf(f.z, mr, acc2[4 * q + 2]);
      acc2[4 * q + 3] = fmaf(f.w, mr, acc2[4 * q + 3]);
    }
  }

  float* op = out + ((size_t)b * Nn + n) * Dd + o0;
#pragma unroll
  for (int q = 0; q < 8; ++q) {
    float4 v;
    v.x = acc2[4 * q + 0] + res[q].x * 0.25f;
    v.y = acc2[4 * q + 1] + res[q].y * 0.25f;
    v.z = acc2[4 * q + 2] + res[q].z * 0.25f;
    v.w = acc2[4 * q + 3] + res[q].w * 0.25f;
    ((float4*)op)[q] = v;
  }
}

extern "C" void kernel_launch(void* const* d_in, const int* in_sizes, int n_in,
                              void* d_out, int out_size, void* d_ws, size_t ws_size,
                              hipStream_t stream) {
  const float* x          = (const float*)d_in[0];
  const float* factors    = (const float*)d_in[1];
  const float* factor_out = (const float*)d_in[2];
  const float* gain       = (const float*)d_in[3];
  float* out              = (float*)d_out;
  hipLaunchKernelGGL(cpquad_kernel, dim3(Nn), dim3(256), 0, stream,
                     x, factors, factor_out, gain, out);
}

// Round 3
// 375.717 us; speedup vs baseline: 2.3269x; 1.9438x over previous
//
#include <hip/hip_runtime.h>

// CPQuadRankLayer: B=64, N=1024, C=4, R=64, D=128, fp32.
//   projected[b,n,c,r] = sum_i x[b,n,c,i] * factors[c,n,r,i]
//   p = projected * rsqrt(mean_r(projected^2) + 1e-6)
//   merged[b,n,r] = p0*p1*p2*p3 * gain[n]
//   out[b,n,o] = sum_r merged[b,n,r]*factor_out[n,r,o] + 0.25*sum_c x[b,n,c,o]
//
// R3: register-tiled GEMM. Block per n; wave=c; lane=(bg,rg)=8x8 grid;
// acc tile 8b x 8r per lane (FULL unroll everywhere acc is indexed --
// R2's partial unrolls put acc[] in scratch: 626MB WRITE_SIZE, 4x slowdown).
// x and f DMA-staged (global_load_lds 16B) into dbuf LDS chunks of 8 i's,
// XOR slot swizzle (DMA forbids padding) -> 2-way bank alias = free.
// One ds_read_b128 feeds 32 FMAs. launch_bounds(256,2): no-spill guarantee.

constexpr int Nn = 1024;
constexpr int Cc = 4;
constexpr int Dd = 128;
constexpr int Rr = 64;
constexpr int IC = 8;             // i-chunk depth
constexpr int NCH = Dd / IC;      // 16 chunks

typedef __attribute__((address_space(3))) float lds_float;
typedef __attribute__((address_space(1))) const float gbl_float;

// async global->LDS: per-lane global src, wave-uniform LDS base (+lane*16 by HW)
__device__ __forceinline__ void ald16(const float* g, const float* l) {
  __builtin_amdgcn_global_load_lds((gbl_float*)g,
                                   (lds_float*)(uint32_t)(uintptr_t)l,
                                   16, 0, 0);
}

__device__ __forceinline__ int row_of_slot(int s) {
  const int a = s >> 3;
  return 8 * a + ((s & 7) ^ a);   // inverse of slot(8a+j)=8a+(j^a)
}

__global__ __launch_bounds__(256, 2)
void cpquad_kernel(const float* __restrict__ x,
                   const float* __restrict__ factors,
                   const float* __restrict__ factor_out,
                   const float* __restrict__ gain,
                   float* __restrict__ out) {
  // 32 KiB staging: f region [0,4096): (p*4+c)*512 + slot*8 + i
  //                 x region [4096,8192): same indexing
  // Reused flat as factor_out[n] ([64r][128o]) in phase 4.
  __shared__ alignas(16) float Sbuf[8192];
  // pT[r][b]: transposed merged-product buffer; stride 72 -> 2-way banks, 16B ok
  __shared__ alignas(16) float pT[Rr][72];

  const int n   = blockIdx.x;
  const int tid = threadIdx.x;
  const int c   = tid >> 6;       // wave = child
  const int l   = tid & 63;
  const int bg  = l & 7;          // b-group
  const int rg  = l >> 3;         // r-group (also o-group in phase 4)
  const int h   = l & 1;

  // ---- DMA source addresses (slot-swizzled rows) ----
  const int s0 = l >> 1, s1 = 32 + (l >> 1);
  const int r0 = row_of_slot(s0), r1 = row_of_slot(s1);
  const float* fcn = factors + (((size_t)c * Nn + n) * Rr) * Dd;
  const float* fsrc0 = fcn + r0 * Dd + h * 4;
  const float* fsrc1 = fcn + r1 * Dd + h * 4;
  const float* xsrc0 = x + (((size_t)r0 * Nn + n) * Cc + c) * Dd + h * 4;
  const float* xsrc1 = x + (((size_t)r1 * Nn + n) * Cc + c) * Dd + h * 4;

  // ---- prologue: stage chunk 0 into buffer 0 ----
  {
    float* fw = Sbuf + c * 512;
    float* xw = Sbuf + 4096 + c * 512;
    ald16(fsrc0, fw);  ald16(fsrc1, fw + 256);
    ald16(xsrc0, xw);  ald16(xsrc1, xw + 256);
  }

  float acc[8][8];
#pragma unroll
  for (int kk = 0; kk < 8; ++kk)
#pragma unroll
    for (int jj = 0; jj < 8; ++jj) acc[kk][jj] = 0.0f;

  // LDS read offsets (floats) for this lane's 8 f-rows / 8 x-rows
  int fof[8], xof[8];
#pragma unroll
  for (int t = 0; t < 8; ++t) {
    fof[t] = (8 * rg + (t ^ rg)) * 8;
    xof[t] = (8 * bg + (t ^ bg)) * 8;
  }

  __syncthreads();  // chunk-0 DMA drained

  // ---------------- Phase 1: projection GEMM ----------------
#pragma unroll 1
  for (int ch = 0; ch < NCH; ++ch) {
    const int p = ch & 1;
    if (ch + 1 < NCH) {
      const int i0 = (ch + 1) * IC;
      float* fw = Sbuf + ((p ^ 1) * 4 + c) * 512;
      float* xw = Sbuf + 4096 + ((p ^ 1) * 4 + c) * 512;
      ald16(fsrc0 + i0, fw);  ald16(fsrc1 + i0, fw + 256);
      ald16(xsrc0 + i0, xw);  ald16(xsrc1 + i0, xw + 256);
    }
    const float* fr = Sbuf + (p * 4 + c) * 512;
    const float* xr = Sbuf + 4096 + (p * 4 + c) * 512;
#pragma unroll
    for (int hh = 0; hh < 2; ++hh) {
      float4 fv[8], xv[8];
#pragma unroll
      for (int jj = 0; jj < 8; ++jj)
        fv[jj] = *(const float4*)(fr + fof[jj] + hh * 4);
#pragma unroll
      for (int kk = 0; kk < 8; ++kk)
        xv[kk] = *(const float4*)(xr + xof[kk] + hh * 4);
#pragma unroll
      for (int kk = 0; kk < 8; ++kk)
#pragma unroll
        for (int jj = 0; jj < 8; ++jj) {
          float a = acc[kk][jj];
          a = fmaf(xv[kk].x, fv[jj].x, a);
          a = fmaf(xv[kk].y, fv[jj].y, a);
          a = fmaf(xv[kk].z, fv[jj].z, a);
          a = fmaf(xv[kk].w, fv[jj].w, a);
          acc[kk][jj] = a;
        }
    }
    __syncthreads();  // buf p consumed; next iter's DMA may overwrite it
  }

  // ---- stage factor_out[n] (32 KiB flat) into Sbuf (phase-1 data dead) ----
  {
    const float* fog = factor_out + (size_t)n * Rr * Dd;
#pragma unroll
    for (int k = 0; k < 8; ++k) {
      const int sec = k * 4 + c;                    // wave-uniform
      ald16(fog + sec * 256 + l * 4, Sbuf + sec * 256);
    }
  }

  // ---------------- Phase 2: RMSNorm over r ----------------
  float scale[8];
  {
    const float g = gain[n];
#pragma unroll
    for (int kk = 0; kk < 8; ++kk) {
      float s = 0.0f;
#pragma unroll
      for (int jj = 0; jj < 8; ++jj) s = fmaf(acc[kk][jj], acc[kk][jj], s);
      s += __shfl_xor(s, 8);      // reduce across rg (lane bits 3..5)
      s += __shfl_xor(s, 16);
      s += __shfl_xor(s, 32);
      float sc = 1.0f / sqrtf(s * (1.0f / 64.0f) + 1e-6f);
      if (c == 0) sc *= g;        // fold gain once into child 0
      scale[kk] = sc;
    }
  }

  // ---------------- Phase 3: quartic product into pT[r][b] --------------
#pragma unroll
  for (int w = 0; w < 4; ++w) {
    if (c == w) {
#pragma unroll
      for (int jj = 0; jj < 8; ++jj) {
        float4 lo, hi;
        lo.x = acc[0][jj] * scale[0];  lo.y = acc[1][jj] * scale[1];
        lo.z = acc[2][jj] * scale[2];  lo.w = acc[3][jj] * scale[3];
        hi.x = acc[4][jj] * scale[4];  hi.y = acc[5][jj] * scale[5];
        hi.z = acc[6][jj] * scale[6];  hi.w = acc[7][jj] * scale[7];
        float4* dst = (float4*)&pT[8 * rg + jj][8 * bg];
        if (w == 0) {
          dst[0] = lo;  dst[1] = hi;
        } else {
          float4 a0 = dst[0], a1 = dst[1];
          a0.x *= lo.x; a0.y *= lo.y; a0.z *= lo.z; a0.w *= lo.w;
          a1.x *= hi.x; a1.y *= hi.y; a1.z *= hi.z; a1.w *= hi.w;
          dst[0] = a0;  dst[1] = a1;
        }
      }
    }
    __syncthreads();  // order passes; also drains fo DMA by the last one
  }

  // ---------------- Phase 4: output projection ----------------
  // wave c owns o in [32c, 32c+32); lane tile 8b x 4o
  const int o0 = c * 32 + rg * 4;
  float4 a2[8];
#pragma unroll
  for (int kk = 0; kk < 8; ++kk) a2[kk] = make_float4(0.f, 0.f, 0.f, 0.f);

#pragma unroll 4
  for (int r = 0; r < Rr; ++r) {
    const float4 m0 = *(const float4*)&pT[r][8 * bg];
    const float4 m1 = *(const float4*)&pT[r][8 * bg + 4];
    const float4 f  = *(const float4*)(Sbuf + r * Dd + o0);
    a2[0].x = fmaf(m0.x, f.x, a2[0].x); a2[0].y = fmaf(m0.x, f.y, a2[0].y);
    a2[0].z = fmaf(m0.x, f.z, a2[0].z); a2[0].w = fmaf(m0.x, f.w, a2[0].w);
    a2[1].x = fmaf(m0.y, f.x, a2[1].x); a2[1].y = fmaf(m0.y, f.y, a2[1].y);
    a2[1].z = fmaf(m0.y, f.z, a2[1].z); a2[1].w = fmaf(m0.y, f.w, a2[1].w);
    a2[2].x = fmaf(m0.z, f.x, a2[2].x); a2[2].y = fmaf(m0.z, f.y, a2[2].y);
    a2[2].z = fmaf(m0.z, f.z, a2[2].z); a2[2].w = fmaf(m0.z, f.w, a2[2].w);
    a2[3].x = fmaf(m0.w, f.x, a2[3].x); a2[3].y = fmaf(m0.w, f.y, a2[3].y);
    a2[3].z = fmaf(m0.w, f.z, a2[3].z); a2[3].w = fmaf(m0.w, f.w, a2[3].w);
    a2[4].x = fmaf(m1.x, f.x, a2[4].x); a2[4].y = fmaf(m1.x, f.y, a2[4].y);
    a2[4].z = fmaf(m1.x, f.z, a2[4].z); a2[4].w = fmaf(m1.x, f.w, a2[4].w);
    a2[5].x = fmaf(m1.y, f.x, a2[5].x); a2[5].y = fmaf(m1.y, f.y, a2[5].y);
    a2[5].z = fmaf(m1.y, f.z, a2[5].z); a2[5].w = fmaf(m1.y, f.w, a2[5].w);
    a2[6].x = fmaf(m1.z, f.x, a2[6].x); a2[6].y = fmaf(m1.z, f.y, a2[6].y);
    a2[6].z = fmaf(m1.z, f.z, a2[6].z); a2[6].w = fmaf(m1.z, f.w, a2[6].w);
    a2[7].x = fmaf(m1.w, f.x, a2[7].x); a2[7].y = fmaf(m1.w, f.y, a2[7].y);
    a2[7].z = fmaf(m1.w, f.z, a2[7].z); a2[7].w = fmaf(m1.w, f.w, a2[7].w);
  }

  // ---------------- epilogue: residual + store ----------------
#pragma unroll
  for (int kk = 0; kk < 8; ++kk) {
    const int b = 8 * bg + kk;
    const float* xb = x + (((size_t)b * Nn + n) * Cc) * Dd + o0;
    float4 t0 = *(const float4*)(xb);
    float4 t1 = *(const float4*)(xb + Dd);
    float4 t2 = *(const float4*)(xb + 2 * Dd);
    float4 t3 = *(const float4*)(xb + 3 * Dd);
    float4 v;
    v.x = a2[kk].x + 0.25f * (t0.x + t1.x + t2.x + t3.x);
    v.y = a2[kk].y + 0.25f * (t0.y + t1.y + t2.y + t3.y);
    v.z = a2[kk].z + 0.25f * (t0.z + t1.z + t2.z + t3.z);
    v.w = a2[kk].w + 0.25f * (t0.w + t1.w + t2.w + t3.w);
    *(float4*)(out + ((size_t)b * Nn + n) * Dd + o0) = v;
  }
}

extern "C" void kernel_launch(void* const* d_in, const int* in_sizes, int n_in,
                              void* d_out, int out_size, void* d_ws, size_t ws_size,
                              hipStream_t stream) {
  const float* x          = (const float*)d_in[0];
  const float* factors    = (const float*)d_in[1];
  const float* factor_out = (const float*)d_in[2];
  const float* gain       = (const float*)d_in[3];
  float* out              = (float*)d_out;
  hipLaunchKernelGGL(cpquad_kernel, dim3(Nn), dim3(256), 0, stream,
                     x, factors, factor_out, gain, out);
}